// Round 8
// baseline (368.791 us; speedup 1.0000x reference)
//
#include <hip/hip_runtime.h>

typedef __attribute__((ext_vector_type(8))) short short8;
typedef __attribute__((ext_vector_type(4))) float floatx4;

#define B_ 2
#define T_ 2048
#define DM_ 2048
#define H_ 16
#define D_ 128
#define HALF_ 64

__device__ inline unsigned short f2bf(float f) {
    union { float f; unsigned u; } v; v.f = f;
    unsigned r = (v.u + 0x7fffu + ((v.u >> 16) & 1u)) >> 16;
    return (unsigned short)r;
}

__device__ inline void gld16(const void* g, void* l) {
    __builtin_amdgcn_global_load_lds(
        (__attribute__((address_space(1))) void*)g,
        (__attribute__((address_space(3))) void*)l,
        16, 0, 0);
}

// ---------------- fused fp32 -> bf16 convert: x (2 slices) + 4 weights ----------------
__global__ void conv_all(const float* __restrict__ x,
                         const float* __restrict__ w0, const float* __restrict__ w1,
                         const float* __restrict__ w2, const float* __restrict__ w3,
                         unsigned short* __restrict__ xb,
                         unsigned short* __restrict__ wb, int n4w) {
    int y = blockIdx.y;
    int i = blockIdx.x * 256 + threadIdx.x;
    const float* src;
    ushort4* dst;
    if (y < 2) { src = x + (size_t)y * n4w * 4; dst = (ushort4*)xb + (size_t)y * n4w; }
    else {
        src = (y == 2) ? w0 : (y == 3) ? w1 : (y == 4) ? w2 : w3;
        dst = (ushort4*)wb + (size_t)(y - 2) * n4w;
    }
    float4 f = ((const float4*)src)[i];
    ushort4 o;
    o.x = f2bf(f.x); o.y = f2bf(f.y); o.z = f2bf(f.z); o.w = f2bf(f.w);
    dst[i] = o;
}

// ---------------- fused QKV GEMM + RoPE + V-transpose (BK=64) ----------------
__global__ __launch_bounds__(256)
void gemm_qkv(const unsigned short* __restrict__ A,
              const unsigned short* __restrict__ W,
              unsigned short* __restrict__ q,
              unsigned short* __restrict__ k,
              unsigned short* __restrict__ vt,
              const float* __restrict__ cosT,
              const float* __restrict__ sinT) {
    __shared__ unsigned short sh[18432];
    unsigned short* As = sh;
    unsigned short* Bs = sh + 8192;

    const int t    = threadIdx.x;
    const int lane = t & 63;
    const int w    = t >> 6;
    const int wm   = w >> 1, wn = w & 1;
    const int l15  = lane & 15, quad = lane >> 4;
    const int bx   = blockIdx.x;
    const int row0 = blockIdx.y * 128;
    const int colg0 = bx * 128;
    const int h     = bx & 15;
    const int K = DM_;

    floatx4 acc[4][4];
    for (int i = 0; i < 4; ++i)
        for (int j = 0; j < 4; ++j)
            acc[i][j] = (floatx4){0.f, 0.f, 0.f, 0.f};

    for (int kt = 0; kt < K / 64; ++kt) {
        if (kt) __syncthreads();
        for (int i = 0; i < 4; ++i) {
            int g  = i * 256 + t;
            int g0 = i * 256 + (t & ~63);
            int m  = g >> 3, c = g & 7;
            int k8 = c ^ (m & 7);
            gld16(A + (size_t)(row0 + m) * K + kt * 64 + k8 * 8, As + (size_t)g0 * 8);
            gld16(W + (size_t)(colg0 + m) * K + kt * 64 + k8 * 8, Bs + (size_t)g0 * 8);
        }
        __syncthreads();

        for (int s = 0; s < 2; ++s) {
            short8 a[4], b[4];
            for (int mf = 0; mf < 4; ++mf) {
                int row = wm * 64 + mf * 16 + l15;
                int pc  = (quad + s * 4) ^ (row & 7);
                a[mf] = *(const short8*)(As + row * 64 + pc * 8);
            }
            for (int nf = 0; nf < 4; ++nf) {
                int row = wn * 32 + (nf & 1) * 16 + (nf >> 1) * 64 + l15;
                int pc  = (quad + s * 4) ^ (row & 7);
                b[nf] = *(const short8*)(Bs + row * 64 + pc * 8);
            }
            for (int mf = 0; mf < 4; ++mf)
                for (int nf = 0; nf < 4; ++nf)
                    acc[mf][nf] = __builtin_amdgcn_mfma_f32_16x16x32_bf16(
                        a[mf], b[nf], acc[mf][nf], 0, 0, 0);
        }
    }

    if (bx < 32) {
        unsigned short* C = (bx < 16) ? q : k;
        for (int mf = 0; mf < 4; ++mf) {
            for (int nf = 0; nf < 2; ++nf) {
                int dh = wn * 32 + nf * 16 + l15;
                for (int r = 0; r < 4; ++r) {
                    int rowg = row0 + wm * 64 + mf * 16 + quad * 4 + r;
                    int tt = rowg & 2047;
                    float c = cosT[tt * 64 + dh];
                    float s = sinT[tt * 64 + dh];
                    float x1 = acc[mf][nf][r];
                    float x2 = acc[mf][nf + 2][r];
                    size_t base = (size_t)rowg * DM_ + h * D_ + dh;
                    C[base]         = f2bf(x1 * c - x2 * s);
                    C[base + HALF_] = f2bf(x1 * s + x2 * c);
                }
            }
        }
    } else {
        __syncthreads();
        unsigned short* P = sh + w * 4608;
        for (int mf = 0; mf < 4; ++mf)
            for (int nf = 0; nf < 4; ++nf) {
                int lc = nf * 16 + l15;
                ushort4 o4;
                o4.x = f2bf(acc[mf][nf][0]); o4.y = f2bf(acc[mf][nf][1]);
                o4.z = f2bf(acc[mf][nf][2]); o4.w = f2bf(acc[mf][nf][3]);
                *(ushort4*)(P + lc * 72 + mf * 16 + quad * 4) = o4;
            }
        __syncthreads();
        const int b  = row0 >> 11;
        const int t0 = (row0 & 2047) + wm * 64;
        for (int it = 0; it < 8; ++it) {
            int cidx = it * 64 + lane;
            int lc = cidx >> 3, t8 = cidx & 7;
            int dh = wn * 32 + ((lc >> 4) & 1) * 16 + (lc >> 5) * 64 + (lc & 15);
            uint4 d = *(const uint4*)(P + lc * 72 + t8 * 8);
            *(uint4*)(vt + ((size_t)(b * 16 + h) * 128 + dh) * T_ + t0 + t8 * 8) = d;
        }
    }
}

// ---------------- bf16 GEMM (fp32 out, BK=64) ----------------
__global__ __launch_bounds__(256)
void gemm_bt(const unsigned short* __restrict__ A,
             const unsigned short* __restrict__ W,
             float* __restrict__ C, int M, int N, int K) {
    __shared__ unsigned short As[128 * 64];
    __shared__ unsigned short Bs[128 * 64];

    const int t    = threadIdx.x;
    const int lane = t & 63;
    const int w    = t >> 6;
    const int wm   = w >> 1, wn = w & 1;
    const int l15  = lane & 15, quad = lane >> 4;
    const int row0 = blockIdx.y * 128, col0 = blockIdx.x * 128;

    floatx4 acc[4][4];
    for (int i = 0; i < 4; ++i)
        for (int j = 0; j < 4; ++j)
            acc[i][j] = (floatx4){0.f, 0.f, 0.f, 0.f};

    const int nkt = K >> 6;
    for (int kt = 0; kt < nkt; ++kt) {
        if (kt) __syncthreads();
        for (int i = 0; i < 4; ++i) {
            int g  = i * 256 + t;
            int g0 = i * 256 + (t & ~63);
            int m  = g >> 3, c = g & 7;
            int k8 = c ^ (m & 7);
            gld16(A + (size_t)(row0 + m) * K + kt * 64 + k8 * 8,
                  (unsigned short*)As + (size_t)g0 * 8);
            gld16(W + (size_t)(col0 + m) * K + kt * 64 + k8 * 8,
                  (unsigned short*)Bs + (size_t)g0 * 8);
        }
        __syncthreads();

        for (int s = 0; s < 2; ++s) {
            short8 a[4], b[4];
            for (int mf = 0; mf < 4; ++mf) {
                int row = wm * 64 + mf * 16 + l15;
                int pc  = (quad + s * 4) ^ (row & 7);
                a[mf] = *(const short8*)(As + row * 64 + pc * 8);
            }
            for (int nf = 0; nf < 4; ++nf) {
                int row = wn * 64 + nf * 16 + l15;
                int pc  = (quad + s * 4) ^ (row & 7);
                b[nf] = *(const short8*)(Bs + row * 64 + pc * 8);
            }
            for (int mf = 0; mf < 4; ++mf)
                for (int nf = 0; nf < 4; ++nf)
                    acc[mf][nf] = __builtin_amdgcn_mfma_f32_16x16x32_bf16(
                        a[mf], b[nf], acc[mf][nf], 0, 0, 0);
        }
    }

    for (int mf = 0; mf < 4; ++mf)
        for (int nf = 0; nf < 4; ++nf)
            for (int r = 0; r < 4; ++r) {
                int row = row0 + wm * 64 + mf * 16 + quad * 4 + r;
                int col = col0 + wn * 64 + nf * 16 + l15;
                C[(size_t)row * N + col] = acc[mf][nf][r];
            }
}

// ---------------- causal flash attention, 8-wave blocks (two qt-pairs) ----------------
// grid (8, B*H), block 512. Block bx handles pairs (j0,31-j0) and (j0+1,30-j0).
// gld16 LDS dest is WAVE-UNIFORM base (it*512 shorts); lane offset is implicit lane*16B.
__global__ __launch_bounds__(512)
void attn_kernel(const unsigned short* __restrict__ q,
                 const unsigned short* __restrict__ k,
                 const unsigned short* __restrict__ vt,
                 unsigned short* __restrict__ ao) {
    __shared__ unsigned short Ks[64 * 128];    // 16 KB
    __shared__ unsigned short Vts[128 * 64];   // 16 KB
    __shared__ unsigned short Pw[8][16 * 72];  // 18.4 KB

    const int t    = threadIdx.x;
    const int lane = t & 63, w = t >> 6;       // w 0..7
    const int w4   = w & 3;
    const int l15  = lane & 15, quad = lane >> 4;
    const int j0   = blockIdx.x * 2;
    const int jj   = j0 + (w >> 2);
    const int bh   = blockIdx.y;
    const int b    = bh >> 4, h = bh & 15;
    const int qt[2] = {31 - jj, jj};

    const size_t hoff  = (size_t)h * D_;
    const size_t bbase = (size_t)b * T_ * DM_;

    short8 qa[2][4];
    for (int rs = 0; rs < 2; ++rs) {
        const int qw = qt[rs] * 64 + w4 * 16;
        const unsigned short* qp = q + bbase + (size_t)(qw + l15) * DM_ + hoff + quad * 8;
        for (int ds = 0; ds < 4; ++ds)
            qa[rs][ds] = *(const short8*)(qp + ds * 32);
    }

    floatx4 o[2][8];
    floatx4 lacc[2];
    for (int rs = 0; rs < 2; ++rs) {
        for (int c = 0; c < 8; ++c) o[rs][c] = (floatx4){0.f, 0.f, 0.f, 0.f};
        lacc[rs] = (floatx4){0.f, 0.f, 0.f, 0.f};
    }
    const unsigned short one_bf = 0x3F80;
    short8 ones;
    for (int i = 0; i < 8; ++i) ones[i] = (short)one_bf;

    const float kS = 0.08838834764831845f;
    const int ktend = 31 - j0;

    for (int kt = 0; kt <= ktend; ++kt) {
        if (kt) __syncthreads();
        // stage K [64][128] and Vt [128][64]: 16 wave-iters of 1024B each
        for (int i = 0; i < 2; ++i) {
            int it = w * 2 + i;                // 0..15
            int krow = it * 4 + (lane >> 4);
            int gck  = ((lane & 15) ^ (krow & 7));
            gld16(k + bbase + (size_t)(kt * 64 + krow) * DM_ + hoff + gck * 8,
                  (unsigned short*)Ks + it * 512);
            int vrow = it * 8 + (lane >> 3);
            int gcv  = ((lane & 7) ^ (vrow & 7));
            gld16(vt + ((size_t)bh * 128 + vrow) * T_ + kt * 64 + gcv * 8,
                  (unsigned short*)Vts + it * 512);
        }
        __syncthreads();

        for (int rs = 0; rs < 2; ++rs) {
            const int kd = qt[rs];
            if (kt > kd) continue;             // wave-uniform
            const int qw = qt[rs] * 64 + w4 * 16;

            floatx4 s[4];
            for (int f = 0; f < 4; ++f) s[f] = (floatx4){0.f, 0.f, 0.f, 0.f};
            for (int ds = 0; ds < 4; ++ds)
                for (int f = 0; f < 4; ++f) {
                    int krow = f * 16 + l15;
                    int phys = (ds * 4 + quad) ^ (krow & 7);
                    short8 bf = *(const short8*)(Ks + krow * 128 + phys * 8);
                    s[f] = __builtin_amdgcn_mfma_f32_16x16x32_bf16(qa[rs][ds], bf, s[f], 0, 0, 0);
                }

            const bool diag = (kt == kd);
            for (int r = 0; r < 4; ++r) {
                int qrow = qw + quad * 4 + r;
                for (int f = 0; f < 4; ++f) {
                    float x = s[f][r] * kS;
                    float e = __expf(x);
                    if (diag && (kt * 64 + f * 16 + l15 > qrow)) e = 0.f;
                    Pw[w][(quad * 4 + r) * 72 + f * 16 + l15] = f2bf(e);
                }
            }

            short8 pa0 = *(const short8*)(&Pw[w][l15 * 72 + quad * 8]);
            short8 pa1 = *(const short8*)(&Pw[w][l15 * 72 + 32 + quad * 8]);
            lacc[rs] = __builtin_amdgcn_mfma_f32_16x16x32_bf16(pa0, ones, lacc[rs], 0, 0, 0);
            lacc[rs] = __builtin_amdgcn_mfma_f32_16x16x32_bf16(pa1, ones, lacc[rs], 0, 0, 0);
            for (int c = 0; c < 8; ++c) {
                int vrow = c * 16 + l15;
                short8 b0 = *(const short8*)(Vts + vrow * 64 + ((quad) ^ (vrow & 7)) * 8);
                short8 b1 = *(const short8*)(Vts + vrow * 64 + ((4 + quad) ^ (vrow & 7)) * 8);
                o[rs][c] = __builtin_amdgcn_mfma_f32_16x16x32_bf16(pa0, b0, o[rs][c], 0, 0, 0);
                o[rs][c] = __builtin_amdgcn_mfma_f32_16x16x32_bf16(pa1, b1, o[rs][c], 0, 0, 0);
            }
        }
    }

    for (int rs = 0; rs < 2; ++rs) {
        const int qw = qt[rs] * 64 + w4 * 16;
        for (int r = 0; r < 4; ++r) {
            float inv = 1.0f / lacc[rs][r];
            int qrow = qw + quad * 4 + r;
            size_t obase = bbase + (size_t)qrow * DM_ + hoff;
            for (int c = 0; c < 8; ++c)
                ao[obase + c * 16 + l15] = f2bf(o[rs][c][r] * inv);
        }
    }
}

extern "C" void kernel_launch(void* const* d_in, const int* in_sizes, int n_in,
                              void* d_out, int out_size, void* d_ws, size_t ws_size,
                              hipStream_t stream) {
    const float* x    = (const float*)d_in[0];
    const float* wq   = (const float*)d_in[1];
    const float* wk   = (const float*)d_in[2];
    const float* wv   = (const float*)d_in[3];
    const float* wo   = (const float*)d_in[4];
    const float* cosT = (const float*)d_in[5];
    const float* sinT = (const float*)d_in[6];
    float* out = (float*)d_out;

    const size_t NX = (size_t)B_ * T_ * DM_;
    const size_t NW = (size_t)DM_ * DM_;

    unsigned short* xb  = (unsigned short*)d_ws;
    unsigned short* wqb = xb + NX;
    unsigned short* wob = wqb + 3 * NW;
    unsigned short* qb  = wob + NW;
    unsigned short* kb  = qb + NX;
    unsigned short* vtb = kb + NX;
    unsigned short* aob = vtb + NX;

    conv_all<<<dim3((int)(NW / 4 / 256), 6), 256, 0, stream>>>(
        x, wq, wk, wv, wo, xb, wqb, (int)(NW / 4));

    gemm_qkv<<<dim3(48, 32), 256, 0, stream>>>(xb, wqb, qb, kb, vtb, cosT, sinT);

    attn_kernel<<<dim3(8, B_ * H_), 512, 0, stream>>>(qb, kb, vtb, aob);

    gemm_bt<<<dim3(16, 32), 256, 0, stream>>>(aob, wob, out, B_ * T_, DM_, DM_);
}